// Round 15
// baseline (146.293 us; speedup 1.0000x reference)
//
#include <hip/hip_runtime.h>

// DialogueGCN on MI355X — round 14: gather-on-h (narrow) + mix-GEMM after.
// R11-R13 post-mortem: gather-on-P needs 3 panel loads per band row; all
// restructurings regressed. This round uses gather(h)@W == gather(h@W):
// aggregate 512-col h first (21 u32 loads/thread, one load -> 3 outputs),
// then one K=2048 GEMM per layer. All proven pieces kept (guards, swizzled
// BK=64 GEMM core, XCD swizzle, fused fp32 scores, split-bf16 y).
// Pipeline: prep -> y_gemm -> gatherZ1(scores+agg) -> mix1 -> gatherZ2 -> mix2.

#define NN 4096

typedef __bf16 bf16x8 __attribute__((ext_vector_type(8)));
typedef float f32x4 __attribute__((ext_vector_type(4)));
typedef unsigned short u16;
typedef unsigned int u32;

__device__ __forceinline__ u16 f2bf(float f) {
  unsigned u = __float_as_uint(f);
  unsigned r = u + 0x7FFFu + ((u >> 16) & 1u);
  return (u16)(r >> 16);
}
__device__ __forceinline__ float bf2f(u16 h) {
  return __uint_as_float(((unsigned)h) << 16);
}
__device__ __forceinline__ float blo(u32 v) { return __uint_as_float(v << 16); }
__device__ __forceinline__ float bhi(u32 v) { return __uint_as_float(v & 0xffff0000u); }
__device__ __forceinline__ u32 packbf(float a, float b) {
  return (u32)f2bf(a) | ((u32)f2bf(b) << 16);
}

__device__ __forceinline__ void gload_lds16(const u16* g, u16* l) {
  __builtin_amdgcn_global_load_lds(
      (const __attribute__((address_space(1))) void*)g,
      (__attribute__((address_space(3))) void*)l, 16, 0, 0);
}

// ---------------- fused prep ----------------
// A [0,8192):      x -> Aatt [hi|lo|hi]; xp[r+16]=x (f32); xbg[r+16]=bf16(x)
// B [8192,9216):   w_att -> Batt [512][1536] = [hi|hi|lo]
// W [9216,17408):  Wtc[512 j][2048 k] x2; k-panels: gc0-gc1 | gc2-gc3 | gc1+gc3 | aggr
// [17408,17472): xp guards   [17472,17536): xbg guards
// [17536,17600): h1g guards  [17600,17617): spkp guarded copy
__global__ void prep_all(const float* __restrict__ x, const float* __restrict__ w_att,
                         const float* __restrict__ w_gc1, const float* __restrict__ w_aggr1,
                         const float* __restrict__ w_gc2, const float* __restrict__ w_aggr2,
                         const int* __restrict__ spk,
                         u16* __restrict__ Aatt, u16* __restrict__ Batt,
                         u16* __restrict__ Wt1c, u16* __restrict__ Wt2c,
                         float* __restrict__ xp, u16* __restrict__ xbg,
                         u16* __restrict__ h1g, int* __restrict__ spkp) {
  const int b = blockIdx.x, tid = threadIdx.x;
  if (b < 8192) {
    int idx = b * 256 + tid;
    int r = idx >> 9, c = idx & 511;
    float v = x[idx];
    u16 hi = f2bf(v), lo = f2bf(v - bf2f(hi));
    u16* row = Aatt + (size_t)r * 1536;
    row[c] = hi; row[512 + c] = lo; row[1024 + c] = hi;
    xp[(size_t)(r + 16) * 512 + c] = v;
    xbg[(size_t)(r + 16) * 512 + c] = hi;
  } else if (b < 9216) {
    int idx = (b - 8192) * 256 + tid;
    int j = idx >> 9, e = idx & 511;
    float v = w_att[(size_t)e * 512 + j];
    u16 hi = f2bf(v), lo = f2bf(v - bf2f(hi));
    u16* row = Batt + (size_t)j * 1536;
    row[e] = hi; row[512 + e] = hi; row[1024 + e] = lo;
  } else if (b < 17408) {
    int lay = (b >= 13312);
    int idx = (b - (lay ? 13312 : 9216)) * 256 + tid;  // over 512*2048
    const float* g = lay ? w_gc2 : w_gc1;
    const float* wa = lay ? w_aggr2 : w_aggr1;
    u16* Wt = lay ? Wt2c : Wt1c;
    int j = idx >> 11, k = idx & 2047;
    int p = k >> 9, kk = k & 511;
    size_t o = (size_t)kk * 512 + j;
    float v;
    if (p == 0)      v = g[o] - g[262144 + o];
    else if (p == 1) v = g[524288 + o] - g[786432 + o];
    else if (p == 2) v = g[262144 + o] + g[786432 + o];
    else             v = wa[o];
    Wt[(size_t)j * 2048 + k] = f2bf(v);
  } else if (b < 17472) {
    int idx = (b - 17408) * 256 + tid;  // 32 rows x 512
    int g = idx >> 9, c = idx & 511;
    int row = (g < 16) ? g : 4112 + (g - 16);
    xp[(size_t)row * 512 + c] = 0.f;
  } else if (b < 17536) {
    int idx = (b - 17472) * 256 + tid;
    int g = idx >> 9, c = idx & 511;
    int row = (g < 16) ? g : 4112 + (g - 16);
    xbg[(size_t)row * 512 + c] = 0;
  } else if (b < 17600) {
    int idx = (b - 17536) * 256 + tid;
    int g = idx >> 9, c = idx & 511;
    int row = (g < 16) ? g : 4112 + (g - 16);
    h1g[(size_t)row * 512 + c] = 0;
  } else {
    int idx = (b - 17600) * 256 + tid;
    if (idx < 4128)
      spkp[idx] = (idx >= 16 && idx < 4112) ? spk[idx - 16] : -9;
  }
}

// XCD-aware swizzle of a 2D grid (total blocks divisible by 8)
__device__ __forceinline__ void xcd_swz(int gx, int& bx, int& by) {
  int lid = by * gx + bx;
  int cpx = (gx * (int)gridDim.y) >> 3;
  int nl = (lid & 7) * cpx + (lid >> 3);
  by = nl / gx;
  bx = nl - by * gx;
}

// ---------------- 128x128 GEMM core — BK=64, swizzled, double-buffered ----------------
__device__ __forceinline__ void gemm_core(const u16* __restrict__ A, const u16* __restrict__ Bt,
                                          int K, int lda, int ldb, size_t bm, size_t bn,
                                          u16 (&As)[2][8192], u16 (&Bs)[2][8192],
                                          f32x4 (&acc)[4][4]) {
  const int tid = threadIdx.x;
  const int lane = tid & 63;
  const int wave = tid >> 6;
  const int wr = wave >> 1, wc = wave & 1;
  const int arow = wr * 64 + (lane & 15);
  const int bcol = wc * 64 + (lane & 15);
  const int nt = K >> 6;

  auto STAGE = [&](int t, int bi) {
    const int k0 = t << 6;
#pragma unroll
    for (int c4 = 0; c4 < 4; ++c4) {
      const int o = (c4 * 256 + tid) * 16;
      const int r = o >> 7;
      const int sc = (((o >> 4) & 7) ^ (r & 7)) << 3;
      gload_lds16(A + (bm + r) * lda + k0 + sc, &As[bi][o >> 1]);
      gload_lds16(Bt + (bn + r) * ldb + k0 + sc, &Bs[bi][o >> 1]);
    }
  };

  STAGE(0, 0);
  for (int t = 0; t < nt; ++t) {
    const int cur = t & 1;
    if (t + 1 < nt) {
      STAGE(t + 1, cur ^ 1);
      asm volatile("s_waitcnt vmcnt(8)" ::: "memory");
    } else {
      asm volatile("s_waitcnt vmcnt(0)" ::: "memory");
    }
    __builtin_amdgcn_s_barrier();
    asm volatile("" ::: "memory");
    bf16x8 af[4][2], bfr[4][2];
#pragma unroll
    for (int i = 0; i < 4; ++i)
#pragma unroll
      for (int ks = 0; ks < 2; ++ks) {
        const int ar = arow + i * 16;
        const int ac = ((ks * 4 + (lane >> 4)) ^ (ar & 7)) << 4;
        af[i][ks] = *(const bf16x8*)((const char*)&As[cur][0] + ar * 128 + ac);
        const int br = bcol + i * 16;
        const int bc = ((ks * 4 + (lane >> 4)) ^ (br & 7)) << 4;
        bfr[i][ks] = *(const bf16x8*)((const char*)&Bs[cur][0] + br * 128 + bc);
      }
#pragma unroll
    for (int ks = 0; ks < 2; ++ks)
#pragma unroll
      for (int i = 0; i < 4; ++i)
#pragma unroll
        for (int j = 0; j < 4; ++j)
          acc[i][j] = __builtin_amdgcn_mfma_f32_16x16x32_bf16(af[i][ks], bfr[j][ks],
                                                              acc[i][j], 0, 0, 0);
    asm volatile("s_waitcnt lgkmcnt(0)" ::: "memory");
    __builtin_amdgcn_sched_barrier(0);
    __builtin_amdgcn_s_barrier();
  }
}

// y = x @ w_att (split-bf16, K=1536, f32 out), M=4096, N=512
__global__ __launch_bounds__(256, 2) void y_gemm(const u16* __restrict__ Aatt,
                                                 const u16* __restrict__ Batt,
                                                 float* __restrict__ y) {
  __shared__ u16 As[2][8192];
  __shared__ u16 Bs[2][8192];
  f32x4 acc[4][4] = {};
  const int tid = threadIdx.x;
  const int lane = tid & 63;
  const int wave = tid >> 6;
  const int wr = wave >> 1, wc = wave & 1;
  int bx = blockIdx.x, by = blockIdx.y;
  xcd_swz(4, bx, by);
  const size_t bm = (size_t)by * 128;
  const size_t bn = (size_t)bx * 128;
  gemm_core(Aatt, Batt, 1536, 1536, 1536, bm, bn, As, Bs, acc);
  const size_t crow = bm + wr * 64 + ((lane >> 4) * 4);
  const size_t ccol = bn + wc * 64 + (lane & 15);
#pragma unroll
  for (int i = 0; i < 4; ++i)
#pragma unroll
    for (int j = 0; j < 4; ++j)
#pragma unroll
      for (int b = 0; b < 4; ++b)
        y[(crow + i * 16 + b) * 512 + ccol + j * 16] = acc[i][j][b];
}

// mix GEMM: out = relu(Z @ Wtc^T), M=4096, N=512, K=2048.
// OUT=1 -> h1g bf16 (+16 guard-row offset); OUT=0 -> d_out f32.
template <int OUT_BF16>
__global__ __launch_bounds__(256, 2) void mix_gemm(const u16* __restrict__ Z,
                                                   const u16* __restrict__ Wtc,
                                                   void* __restrict__ outp) {
  __shared__ u16 As[2][8192];
  __shared__ u16 Bs[2][8192];
  f32x4 acc[4][4] = {};
  const int tid = threadIdx.x;
  const int lane = tid & 63;
  const int wave = tid >> 6;
  const int wr = wave >> 1, wc = wave & 1;
  int bx = blockIdx.x, by = blockIdx.y;
  xcd_swz(4, bx, by);
  const size_t bm = (size_t)by * 128;
  const size_t bn = (size_t)bx * 128;
  gemm_core(Z, Wtc, 2048, 2048, 2048, bm, bn, As, Bs, acc);
  const size_t crow = bm + wr * 64 + ((lane >> 4) * 4);
  const size_t ccol = bn + wc * 64 + (lane & 15);
#pragma unroll
  for (int i = 0; i < 4; ++i)
#pragma unroll
    for (int j = 0; j < 4; ++j)
#pragma unroll
      for (int b = 0; b < 4; ++b) {
        size_t r = crow + i * 16 + b, c = ccol + j * 16;
        float v = fmaxf(acc[i][j][b], 0.f);
        if (OUT_BF16)
          ((u16*)outp)[(r + 16) * 512 + c] = f2bf(v);
        else
          ((float*)outp)[r * 512 + c] = v;
      }
}

// XCD-contiguous row mapping for 4096 one-row blocks
__device__ __forceinline__ int xcd_row(int b) { return (b & 7) * 512 + (b >> 3); }

// ---------------- gatherZ: banded aggregation on narrow h (+fused scores PH1) ----------------
// PH=1: band = xbg (bf16 x), scores+softmax fused (writes attn), Z = [zp|zs|za|x]
// PH=2: band = h1g (bf16 h1), loads attn,        Z = [zp|zs|za|h1]
// One u32 load per band row feeds all three panels (x3 weights). 21 loads/thread.
template <int PH>
__global__ __launch_bounds__(256) void gatherZ(const u16* __restrict__ band,
                                               const float* __restrict__ xp,
                                               const float* __restrict__ y,
                                               float* __restrict__ attn,
                                               const int* __restrict__ spkp,
                                               u32* __restrict__ Z) {
  const int n = xcd_row(blockIdx.x);
  const int tid = threadIdx.x;
  __shared__ float ys[512];
  __shared__ float sc[21];
  __shared__ float av[21], apv[21], asv[21];
  __shared__ int sps[21];
  const int mysp = spkp[16 + n];
  if (tid < 21) sps[tid] = spkp[16 + n - 10 + tid];

  if (PH == 1) {
    ys[tid] = y[(size_t)n * 512 + tid];
    ys[tid + 256] = y[(size_t)n * 512 + tid + 256];
    __syncthreads();
    const int wv = tid >> 6, lane = tid & 63;
    for (int w = wv; w < 21; w += 4) {
      const float* xm = xp + (size_t)(n + 6 + w) * 512;  // zero guards -> OOB dot = 0
      float p = 0.f;
#pragma unroll
      for (int i = 0; i < 8; ++i) p += xm[lane + i * 64] * ys[lane + i * 64];
#pragma unroll
      for (int off = 32; off; off >>= 1) p += __shfl_xor(p, off, 64);
      if (lane == 0) sc[w] = p;
    }
    __syncthreads();
    if (tid < 64) {
      float v = (tid < 21) ? sc[tid] : -1e30f;
      float mx = v;
#pragma unroll
      for (int off = 32; off; off >>= 1) mx = fmaxf(mx, __shfl_xor(mx, off, 64));
      float e = (tid < 21) ? __expf(v - mx) : 0.f;
      float sum = e;
#pragma unroll
      for (int off = 32; off; off >>= 1) sum += __shfl_xor(sum, off, 64);
      if (tid < 21) {
        int m = n + tid - 10;
        float a = (0 <= m && m < NN) ? (e / sum) : 0.f;
        av[tid] = a;
        apv[tid] = (tid >= 10) ? a : 0.f;
        asv[tid] = (sps[tid] == mysp) ? a : 0.f;
        attn[(size_t)n * 24 + tid] = a;
      }
    }
    __syncthreads();
  } else {
    if (tid < 21) {
      int m = n + tid - 10;
      float a = attn[(size_t)n * 24 + tid];
      av[tid] = a;
      apv[tid] = (tid >= 10) ? a : 0.f;
      asv[tid] = (sps[tid] == mysp) ? a : 0.f;
    }
    __syncthreads();
  }

  // ---- narrow banded aggregation: 21 u32 loads, 3 outputs each ----
  const u32* B32 = (const u32*)band + 16 * 256;  // interior row 0
  float zpL = 0, zpH = 0, zsL = 0, zsH = 0, zaL = 0, zaH = 0;
#pragma unroll
  for (int w = 0; w < 21; ++w) {
    const u32 v = B32[(ptrdiff_t)(n - 10 + w) * 256 + tid];  // guards zero
    const float lo = blo(v), hi = bhi(v);
    const float a = av[w], ap = apv[w], as = asv[w];
    zaL += a * lo;  zaH += a * hi;
    zsL += as * lo; zsH += as * hi;
    zpL += ap * lo; zpH += ap * hi;
  }
  u32* zr = Z + (size_t)n * 1024;
  zr[tid] = packbf(zpL, zpH);
  zr[256 + tid] = packbf(zsL, zsH);
  zr[512 + tid] = packbf(zaL, zaH);
  zr[768 + tid] = B32[(ptrdiff_t)n * 256 + tid];  // self panel = h row n
}

// ---------------- launch ----------------
extern "C" void kernel_launch(void* const* d_in, const int* in_sizes, int n_in,
                              void* d_out, int out_size, void* d_ws, size_t ws_size,
                              hipStream_t stream) {
  const float* x = (const float*)d_in[0];
  const int* spk = (const int*)d_in[1];
  const float* w_gc1 = (const float*)d_in[2];
  const float* w_gc2 = (const float*)d_in[3];
  const float* w_att = (const float*)d_in[4];
  const float* w_aggr1 = (const float*)d_in[5];
  const float* w_aggr2 = (const float*)d_in[6];

  char* p = (char*)d_ws;
  u16* Aatt = (u16*)p;  p += (size_t)NN * 1536 * 2;     // 12.6 MB
  u16* Batt = (u16*)p;  p += (size_t)512 * 1536 * 2;    // 1.6 MB
  u16* Wt1c = (u16*)p;  p += (size_t)512 * 2048 * 2;    // 2.1 MB
  u16* Wt2c = (u16*)p;  p += (size_t)512 * 2048 * 2;    // 2.1 MB
  float* xp = (float*)p; p += (size_t)4128 * 512 * 4;   // 8.5 MB
  float* y = (float*)p; p += (size_t)NN * 512 * 4;      // 8.4 MB
  float* attn = (float*)p; p += (size_t)NN * 24 * 4;    // 0.4 MB
  u16* xbg = (u16*)p;   p += (size_t)4128 * 512 * 2;    // 4.2 MB
  u16* h1g = (u16*)p;   p += (size_t)4128 * 512 * 2;    // 4.2 MB
  u16* Z = (u16*)p;     p += (size_t)NN * 2048 * 2;     // 16.8 MB (reused both layers)
  int* spkp = (int*)p;  p += (size_t)4128 * 4;          // 16.5 KB (~61 MB total)

  prep_all<<<17617, 256, 0, stream>>>(x, w_att, w_gc1, w_aggr1, w_gc2, w_aggr2, spk,
                                      Aatt, Batt, Wt1c, Wt2c, xp, xbg, h1g, spkp);

  y_gemm<<<dim3(4, 32), 256, 0, stream>>>(Aatt, Batt, y);

  gatherZ<1><<<NN, 256, 0, stream>>>(xbg, xp, y, attn, spkp, (u32*)Z);

  mix_gemm<1><<<dim3(4, 32), 256, 0, stream>>>(Z, Wt1c, h1g);

  gatherZ<2><<<NN, 256, 0, stream>>>(h1g, xp, y, attn, spkp, (u32*)Z);

  mix_gemm<0><<<dim3(4, 32), 256, 0, stream>>>(Z, Wt2c, d_out);
}

// Round 17
// 102.871 us; speedup vs baseline: 1.4221x; 1.4221x over previous
//
#include <hip/hip_runtime.h>

// DialogueGCN on MI355X — round 16 = round 15 + missing __syncthreads after sps
// store (PH2 race: wave1 read stale speaker LDS -> wrong same-speaker weights).
// 2-rows-per-block gathers (2048 blocks, 22-row shared band), R10 base otherwise.

#define NN 4096

typedef __bf16 bf16x8 __attribute__((ext_vector_type(8)));
typedef float f32x4 __attribute__((ext_vector_type(4)));
typedef unsigned short u16;
typedef unsigned int u32;

__device__ __forceinline__ u16 f2bf(float f) {
  unsigned u = __float_as_uint(f);
  unsigned r = u + 0x7FFFu + ((u >> 16) & 1u);
  return (u16)(r >> 16);
}
__device__ __forceinline__ float bf2f(u16 h) {
  return __uint_as_float(((unsigned)h) << 16);
}
__device__ __forceinline__ float blo(u32 v) { return __uint_as_float(v << 16); }
__device__ __forceinline__ float bhi(u32 v) { return __uint_as_float(v & 0xffff0000u); }
__device__ __forceinline__ u32 packbf(float a, float b) {
  return (u32)f2bf(a) | ((u32)f2bf(b) << 16);
}

__device__ __forceinline__ void gload_lds16(const u16* g, u16* l) {
  __builtin_amdgcn_global_load_lds(
      (const __attribute__((address_space(1))) void*)g,
      (__attribute__((address_space(3))) void*)l, 16, 0, 0);
}

// ---------------- fused prep (guards + spkp) ----------------
__global__ void prep_all(const float* __restrict__ x, const float* __restrict__ w_att,
                         const float* __restrict__ w_gc1, const float* __restrict__ w_aggr1,
                         const float* __restrict__ w_gc2, const float* __restrict__ w_aggr2,
                         const int* __restrict__ spk,
                         u16* __restrict__ Aatt, u16* __restrict__ Batt,
                         u16* __restrict__ Wt1, u16* __restrict__ Wt2,
                         float* __restrict__ xp, u32* __restrict__ xWg,
                         u32* __restrict__ h1Wg, int* __restrict__ spkp) {
  const int b = blockIdx.x, tid = threadIdx.x;
  if (b < 8192) {
    int idx = b * 256 + tid;
    int r = idx >> 9, c = idx & 511;
    float v = x[idx];
    u16 hi = f2bf(v), lo = f2bf(v - bf2f(hi));
    u16* row = Aatt + (size_t)r * 1536;
    row[c] = hi; row[512 + c] = lo; row[1024 + c] = hi;
    xp[(size_t)(r + 16) * 512 + c] = v;
  } else if (b < 9216) {
    int idx = (b - 8192) * 256 + tid;
    int j = idx >> 9, e = idx & 511;
    float v = w_att[(size_t)e * 512 + j];
    u16 hi = f2bf(v), lo = f2bf(v - bf2f(hi));
    u16* row = Batt + (size_t)j * 1536;
    row[e] = hi; row[512 + e] = hi; row[1024 + e] = lo;
  } else if (b < 17408) {
    int lay = (b >= 13312);
    int idx = (b - (lay ? 13312 : 9216)) * 256 + tid;  // over 2048*512
    const float* g = lay ? w_gc2 : w_gc1;
    const float* wa = lay ? w_aggr2 : w_aggr1;
    u16* Wt = lay ? Wt2 : Wt1;
    int j = idx >> 9, k = idx & 511;
    int p = j >> 9, jj = j & 511;
    size_t o = (size_t)k * 512 + jj;
    float v;
    if (p == 0)      v = g[o] - g[262144 + o];
    else if (p == 1) v = g[524288 + o] - g[786432 + o];
    else if (p == 2) v = g[262144 + o] + g[786432 + o];
    else             v = wa[o];
    Wt[(size_t)j * 512 + k] = f2bf(v);
  } else if (b < 17472) {
    int idx = (b - 17408) * 256 + tid;
    int g = idx >> 9, c = idx & 511;
    int row = (g < 16) ? g : 4112 + (g - 16);
    xp[(size_t)row * 512 + c] = 0.f;
  } else if (b < 17600) {
    int idx = (b - 17472) * 256 + tid;
    int g = idx >> 10, c = idx & 1023;
    int row = (g < 16) ? g : 4112 + (g - 16);
    xWg[(size_t)row * 1024 + c] = 0;
  } else if (b < 17728) {
    int idx = (b - 17600) * 256 + tid;
    int g = idx >> 10, c = idx & 1023;
    int row = (g < 16) ? g : 4112 + (g - 16);
    h1Wg[(size_t)row * 1024 + c] = 0;
  } else {
    int idx = (b - 17728) * 256 + tid;
    if (idx < 4128)
      spkp[idx] = (idx >= 16 && idx < 4112) ? spk[idx - 16] : -9;
  }
}

// XCD-aware swizzle of a 2D grid (total blocks divisible by 8)
__device__ __forceinline__ void xcd_swz(int gx, int& bx, int& by) {
  int lid = by * gx + bx;
  int cpx = (gx * (int)gridDim.y) >> 3;
  int nl = (lid & 7) * cpx + (lid >> 3);
  by = nl / gx;
  bx = nl - by * gx;
}

// ---------------- 128x128 GEMM core — BK=64, swizzled, double-buffered ----------------
__device__ __forceinline__ void gemm_core(const u16* __restrict__ A, const u16* __restrict__ Bt,
                                          int K, int lda, int ldb, size_t bm, size_t bn,
                                          u16 (&As)[2][8192], u16 (&Bs)[2][8192],
                                          f32x4 (&acc)[4][4]) {
  const int tid = threadIdx.x;
  const int lane = tid & 63;
  const int wave = tid >> 6;
  const int wr = wave >> 1, wc = wave & 1;
  const int arow = wr * 64 + (lane & 15);
  const int bcol = wc * 64 + (lane & 15);
  const int nt = K >> 6;

  auto STAGE = [&](int t, int bi) {
    const int k0 = t << 6;
#pragma unroll
    for (int c4 = 0; c4 < 4; ++c4) {
      const int o = (c4 * 256 + tid) * 16;
      const int r = o >> 7;
      const int sc = (((o >> 4) & 7) ^ (r & 7)) << 3;
      gload_lds16(A + (bm + r) * lda + k0 + sc, &As[bi][o >> 1]);
      gload_lds16(Bt + (bn + r) * ldb + k0 + sc, &Bs[bi][o >> 1]);
    }
  };

  STAGE(0, 0);
  for (int t = 0; t < nt; ++t) {
    const int cur = t & 1;
    if (t + 1 < nt) {
      STAGE(t + 1, cur ^ 1);
      asm volatile("s_waitcnt vmcnt(8)" ::: "memory");
    } else {
      asm volatile("s_waitcnt vmcnt(0)" ::: "memory");
    }
    __builtin_amdgcn_s_barrier();
    asm volatile("" ::: "memory");
    bf16x8 af[4][2], bfr[4][2];
#pragma unroll
    for (int i = 0; i < 4; ++i)
#pragma unroll
      for (int ks = 0; ks < 2; ++ks) {
        const int ar = arow + i * 16;
        const int ac = ((ks * 4 + (lane >> 4)) ^ (ar & 7)) << 4;
        af[i][ks] = *(const bf16x8*)((const char*)&As[cur][0] + ar * 128 + ac);
        const int br = bcol + i * 16;
        const int bc = ((ks * 4 + (lane >> 4)) ^ (br & 7)) << 4;
        bfr[i][ks] = *(const bf16x8*)((const char*)&Bs[cur][0] + br * 128 + bc);
      }
#pragma unroll
    for (int ks = 0; ks < 2; ++ks)
#pragma unroll
      for (int i = 0; i < 4; ++i)
#pragma unroll
        for (int j = 0; j < 4; ++j)
          acc[i][j] = __builtin_amdgcn_mfma_f32_16x16x32_bf16(af[i][ks], bfr[j][ks],
                                                              acc[i][j], 0, 0, 0);
    asm volatile("s_waitcnt lgkmcnt(0)" ::: "memory");
    __builtin_amdgcn_sched_barrier(0);
    __builtin_amdgcn_s_barrier();
  }
}

// fat GEMM: bx<4 -> y panel (split-bf16, K=1536, f32 out); else xW panel (K=512, bf16)
__global__ __launch_bounds__(256, 2) void fat_gemm(const u16* __restrict__ Aatt,
                                                   const u16* __restrict__ Wt1,
                                                   const u16* __restrict__ Batt,
                                                   u16* __restrict__ xW, float* __restrict__ y) {
  __shared__ u16 As[2][8192];
  __shared__ u16 Bs[2][8192];
  f32x4 acc[4][4] = {};
  const int tid = threadIdx.x;
  const int lane = tid & 63;
  const int wave = tid >> 6;
  const int wr = wave >> 1, wc = wave & 1;
  int bx = blockIdx.x, by = blockIdx.y;
  xcd_swz(20, bx, by);
  const size_t bm = (size_t)by * 128;
  const bool yp = bx < 4;
  const size_t bn = yp ? (size_t)bx * 128 : (size_t)(bx - 4) * 128;

  if (yp)
    gemm_core(Aatt, Batt, 1536, 1536, 1536, bm, bn, As, Bs, acc);
  else
    gemm_core(Aatt, Wt1, 512, 1536, 512, bm, bn, As, Bs, acc);

  const size_t crow = bm + wr * 64 + ((lane >> 4) * 4);
  const size_t ccol = bn + wc * 64 + (lane & 15);
#pragma unroll
  for (int i = 0; i < 4; ++i)
#pragma unroll
    for (int j = 0; j < 4; ++j)
#pragma unroll
      for (int b = 0; b < 4; ++b) {
        size_t r = crow + i * 16 + b, c = ccol + j * 16;
        if (yp)
          y[r * 512 + c] = acc[i][j][b];
        else
          xW[r * 2048 + c] = f2bf(acc[i][j][b]);
      }
}

// layer-2 GEMM: h1W = h1 @ Wt2^T, K=512, bf16 out, ldc=2048
__global__ __launch_bounds__(256, 2) void gemm_l2(const u16* __restrict__ h1,
                                                  const u16* __restrict__ Wt2,
                                                  u16* __restrict__ h1W) {
  __shared__ u16 As[2][8192];
  __shared__ u16 Bs[2][8192];
  f32x4 acc[4][4] = {};
  const int tid = threadIdx.x;
  const int lane = tid & 63;
  const int wave = tid >> 6;
  const int wr = wave >> 1, wc = wave & 1;
  int bx = blockIdx.x, by = blockIdx.y;
  xcd_swz(16, bx, by);
  const size_t bm = (size_t)by * 128;
  const size_t bn = (size_t)bx * 128;
  gemm_core(h1, Wt2, 512, 512, 512, bm, bn, As, Bs, acc);
  const size_t crow = bm + wr * 64 + ((lane >> 4) * 4);
  const size_t ccol = bn + wc * 64 + (lane & 15);
#pragma unroll
  for (int i = 0; i < 4; ++i)
#pragma unroll
    for (int j = 0; j < 4; ++j)
#pragma unroll
      for (int b = 0; b < 4; ++b) {
        size_t r = crow + i * 16 + b, c = ccol + j * 16;
        h1W[r * 2048 + c] = f2bf(acc[i][j][b]);
      }
}

// XCD-contiguous pair mapping: 2048 blocks, block b -> rows [n0, n0+1]
__device__ __forceinline__ int xcd_pair(int b) {
  return ((((b & 7) << 8) + (b >> 3)) << 1);
}

// ---------------- 2-row gather: scores(+softmax) fused in PH1, banded agg ----------------
template <int PH>
__global__ __launch_bounds__(256) void gather2r(const u32* __restrict__ P32,
                                                const float* __restrict__ xp,
                                                const float* __restrict__ y,
                                                float* __restrict__ attn,
                                                const int* __restrict__ spkp,
                                                void* __restrict__ out) {
  const int n0 = xcd_pair(blockIdx.x);
  const int tid = threadIdx.x;
  __shared__ float ys[2][512];
  __shared__ float sc[2][21];
  __shared__ float avs[2][21], asvs[2][21];
  __shared__ int sps[22];

  if (tid < 22) sps[tid] = spkp[16 + n0 - 10 + tid];
  __syncthreads();  // R15 RACE FIX: sps must be visible to all waves (PH2 path)

  if (PH == 1) {
    for (int i = tid; i < 1024; i += 256)
      ys[i >> 9][i & 511] = y[(size_t)(n0 + (i >> 9)) * 512 + (i & 511)];
    __syncthreads();
    const int wv = tid >> 6, lane = tid & 63;
    for (int pidx = wv; pidx < 42; pidx += 4) {
      const int rr = (pidx >= 21) ? 1 : 0;
      const int w = pidx - (rr ? 21 : 0);
      const float* xm = xp + (size_t)(n0 + rr + 6 + w) * 512;  // zero guards
      float p = 0.f;
#pragma unroll
      for (int i = 0; i < 8; ++i) p += xm[lane + i * 64] * ys[rr][lane + i * 64];
#pragma unroll
      for (int off = 32; off; off >>= 1) p += __shfl_xor(p, off, 64);
      if (lane == 0) sc[rr][w] = p;
    }
    __syncthreads();
    if (tid < 128) {
      const int rr = tid >> 6, lane = tid & 63;
      const int n = n0 + rr;
      float v = (lane < 21) ? sc[rr][lane] : -1e30f;
      float mx = v;
#pragma unroll
      for (int off = 32; off; off >>= 1) mx = fmaxf(mx, __shfl_xor(mx, off, 64));
      float e = (lane < 21) ? __expf(v - mx) : 0.f;
      float sum = e;
#pragma unroll
      for (int off = 32; off; off >>= 1) sum += __shfl_xor(sum, off, 64);
      if (lane < 21) {
        int m = n + lane - 10;
        float a = (0 <= m && m < NN) ? (e / sum) : 0.f;
        avs[rr][lane] = a;
        asvs[rr][lane] = (sps[lane + rr] == spkp[16 + n]) ? a : 0.f;
        attn[(size_t)n * 24 + lane] = a;
      }
    }
    __syncthreads();
  } else {
    if (tid < 128) {
      const int rr = tid >> 6, lane = tid & 63;
      const int n = n0 + rr;
      if (lane < 21) {
        float a = attn[(size_t)n * 24 + lane];
        avs[rr][lane] = a;
        asvs[rr][lane] = (sps[lane + rr] == spkp[16 + n]) ? a : 0.f;
      }
    }
    __syncthreads();
  }

  // ---- banded aggregation, both rows, dense static loop ----
  u32 s0 = P32[(size_t)n0 * 1024 + 768 + tid];
  u32 s1 = P32[(size_t)(n0 + 1) * 1024 + 768 + tid];
  float a0L = blo(s0), a0H = bhi(s0);
  float a1L = blo(s1), a1H = bhi(s1);
#pragma unroll
  for (int j = 0; j < 22; ++j) {
    const u32* row = P32 + (ptrdiff_t)(n0 - 10 + j) * 1024 + tid;
    const u32 va = row[512], vs = row[256];
    const float al = blo(va), ah = bhi(va), sl = blo(vs), sh = bhi(vs);
    float pl = 0.f, ph = 0.f;
    if (j >= 10) {
      const u32 vp = row[0];
      pl = blo(vp);
      ph = bhi(vp);
    }
    if (j < 21) {  // row 0: w = j
      const float a = avs[0][j], as = asvs[0][j];
      a0L += a * al + as * sl;
      a0H += a * ah + as * sh;
      if (j >= 10) { a0L += a * pl; a0H += a * ph; }
    }
    if (j >= 1) {  // row 1: w = j - 1
      const float a = avs[1][j - 1], as = asvs[1][j - 1];
      a1L += a * al + as * sl;
      a1H += a * ah + as * sh;
      if (j >= 11) { a1L += a * pl; a1H += a * ph; }
    }
  }
  a0L = fmaxf(a0L, 0.f); a0H = fmaxf(a0H, 0.f);
  a1L = fmaxf(a1L, 0.f); a1H = fmaxf(a1H, 0.f);
  if (PH == 1) {
    ((u32*)out)[(size_t)n0 * 256 + tid] = packbf(a0L, a0H);
    ((u32*)out)[(size_t)(n0 + 1) * 256 + tid] = packbf(a1L, a1H);
  } else {
    float2 v0 = {a0L, a0H}, v1 = {a1L, a1H};
    ((float2*)out)[(size_t)n0 * 256 + tid] = v0;
    ((float2*)out)[(size_t)(n0 + 1) * 256 + tid] = v1;
  }
}

// ---------------- launch ----------------
extern "C" void kernel_launch(void* const* d_in, const int* in_sizes, int n_in,
                              void* d_out, int out_size, void* d_ws, size_t ws_size,
                              hipStream_t stream) {
  const float* x = (const float*)d_in[0];
  const int* spk = (const int*)d_in[1];
  const float* w_gc1 = (const float*)d_in[2];
  const float* w_gc2 = (const float*)d_in[3];
  const float* w_att = (const float*)d_in[4];
  const float* w_aggr1 = (const float*)d_in[5];
  const float* w_aggr2 = (const float*)d_in[6];

  char* p = (char*)d_ws;
  u16* Aatt = (u16*)p;  p += (size_t)NN * 1536 * 2;     // 12.6 MB
  u16* Batt = (u16*)p;  p += (size_t)512 * 1536 * 2;    // 1.6 MB
  u16* Wt1 = (u16*)p;   p += (size_t)2048 * 512 * 2;    // 2.1 MB
  u16* Wt2 = (u16*)p;   p += (size_t)2048 * 512 * 2;    // 2.1 MB
  float* xp = (float*)p; p += (size_t)4128 * 512 * 4;   // 8.5 MB
  float* y = (float*)p; p += (size_t)NN * 512 * 4;      // 8.4 MB
  float* attn = (float*)p; p += (size_t)NN * 24 * 4;    // 0.4 MB
  u16* xWg = (u16*)p;   p += (size_t)4128 * 2048 * 2;   // 16.9 MB
  u16* h1 = (u16*)p;    p += (size_t)NN * 512 * 2;      // 4.2 MB
  u16* h1Wg = (u16*)p;  p += (size_t)4128 * 2048 * 2;   // 16.9 MB
  int* spkp = (int*)p;  p += (size_t)4128 * 4;          // 16.5 KB (~73.6 MB total)

  u16* xW = xWg + (size_t)16 * 2048;
  u16* h1W = h1Wg + (size_t)16 * 2048;

  prep_all<<<17745, 256, 0, stream>>>(x, w_att, w_gc1, w_aggr1, w_gc2, w_aggr2, spk,
                                      Aatt, Batt, Wt1, Wt2, xp, (u32*)xWg, (u32*)h1Wg,
                                      spkp);

  fat_gemm<<<dim3(20, 32), 256, 0, stream>>>(Aatt, Wt1, Batt, xW, y);

  gather2r<1><<<2048, 256, 0, stream>>>((const u32*)xW, xp, y, attn, spkp, h1);

  gemm_l2<<<dim3(16, 32), 256, 0, stream>>>(h1, Wt2, h1W);

  gather2r<2><<<2048, 256, 0, stream>>>((const u32*)h1W, xp, y, attn, spkp, d_out);
}

// Round 18
// 99.192 us; speedup vs baseline: 1.4749x; 1.0371x over previous
//
#include <hip/hip_runtime.h>

// DialogueGCN on MI355X — round 17 = R10 (best, 99.7us) + producer/consumer
// XCD row-alignment: every writer of row r now lands on XCD r>>9, matching the
// gathers' reader mapping (xcd_row). GEMM swizzle: lid%8 == by>>2; prep seg-A
// remapped the same way. Gathers are R10's proven 1-row branch-free version.

#define NN 4096

typedef __bf16 bf16x8 __attribute__((ext_vector_type(8)));
typedef float f32x4 __attribute__((ext_vector_type(4)));
typedef unsigned short u16;
typedef unsigned int u32;

__device__ __forceinline__ u16 f2bf(float f) {
  unsigned u = __float_as_uint(f);
  unsigned r = u + 0x7FFFu + ((u >> 16) & 1u);
  return (u16)(r >> 16);
}
__device__ __forceinline__ float bf2f(u16 h) {
  return __uint_as_float(((unsigned)h) << 16);
}
__device__ __forceinline__ float blo(u32 v) { return __uint_as_float(v << 16); }
__device__ __forceinline__ float bhi(u32 v) { return __uint_as_float(v & 0xffff0000u); }
__device__ __forceinline__ u32 packbf(float a, float b) {
  return (u32)f2bf(a) | ((u32)f2bf(b) << 16);
}

__device__ __forceinline__ void gload_lds16(const u16* g, u16* l) {
  __builtin_amdgcn_global_load_lds(
      (const __attribute__((address_space(1))) void*)g,
      (__attribute__((address_space(3))) void*)l, 16, 0, 0);
}

// ---------------- fused prep ----------------
// seg A XCD-aligned: block b -> row r = 512*(b&7) + (b>>3)/2 (writer XCD == r>>9)
__global__ void prep_all(const float* __restrict__ x, const float* __restrict__ w_att,
                         const float* __restrict__ w_gc1, const float* __restrict__ w_aggr1,
                         const float* __restrict__ w_gc2, const float* __restrict__ w_aggr2,
                         const int* __restrict__ spk,
                         u16* __restrict__ Aatt, u16* __restrict__ Batt,
                         u16* __restrict__ Wt1, u16* __restrict__ Wt2,
                         float* __restrict__ xp, u32* __restrict__ xWg,
                         u32* __restrict__ h1Wg, int* __restrict__ spkp) {
  const int b = blockIdx.x, tid = threadIdx.x;
  if (b < 8192) {
    int s = b >> 3;
    int r = 512 * (b & 7) + (s >> 1);
    int c = ((s & 1) << 8) + tid;
    float v = x[(size_t)r * 512 + c];
    u16 hi = f2bf(v), lo = f2bf(v - bf2f(hi));
    u16* row = Aatt + (size_t)r * 1536;
    row[c] = hi; row[512 + c] = lo; row[1024 + c] = hi;
    xp[(size_t)(r + 16) * 512 + c] = v;
  } else if (b < 9216) {
    int idx = (b - 8192) * 256 + tid;
    int j = idx >> 9, e = idx & 511;
    float v = w_att[(size_t)e * 512 + j];
    u16 hi = f2bf(v), lo = f2bf(v - bf2f(hi));
    u16* row = Batt + (size_t)j * 1536;
    row[e] = hi; row[512 + e] = hi; row[1024 + e] = lo;
  } else if (b < 17408) {
    int lay = (b >= 13312);
    int idx = (b - (lay ? 13312 : 9216)) * 256 + tid;  // over 2048*512
    const float* g = lay ? w_gc2 : w_gc1;
    const float* wa = lay ? w_aggr2 : w_aggr1;
    u16* Wt = lay ? Wt2 : Wt1;
    int j = idx >> 9, k = idx & 511;
    int p = j >> 9, jj = j & 511;
    size_t o = (size_t)k * 512 + jj;
    float v;
    if (p == 0)      v = g[o] - g[262144 + o];
    else if (p == 1) v = g[524288 + o] - g[786432 + o];
    else if (p == 2) v = g[262144 + o] + g[786432 + o];
    else             v = wa[o];
    Wt[(size_t)j * 512 + k] = f2bf(v);
  } else if (b < 17472) {
    int idx = (b - 17408) * 256 + tid;
    int g = idx >> 9, c = idx & 511;
    int row = (g < 16) ? g : 4112 + (g - 16);
    xp[(size_t)row * 512 + c] = 0.f;
  } else if (b < 17600) {
    int idx = (b - 17472) * 256 + tid;
    int g = idx >> 10, c = idx & 1023;
    int row = (g < 16) ? g : 4112 + (g - 16);
    xWg[(size_t)row * 1024 + c] = 0;
  } else if (b < 17728) {
    int idx = (b - 17600) * 256 + tid;
    int g = idx >> 10, c = idx & 1023;
    int row = (g < 16) ? g : 4112 + (g - 16);
    h1Wg[(size_t)row * 1024 + c] = 0;
  } else {
    int idx = (b - 17728) * 256 + tid;
    if (idx < 4128)
      spkp[idx] = (idx >= 16 && idx < 4112) ? spk[idx - 16] : -9;
  }
}

// Row-aligned XCD swizzle: logical row-block by runs on XCD by>>2
// (gridDim.y == 32 -> 4 by per XCD; lid%8 selects XCD by dispatch round-robin).
__device__ __forceinline__ void xcd_align(int gx, int& bx, int& by) {
  int lid = by * gx + bx;
  int xcd = lid & 7;
  int s = lid >> 3;
  int q = s / gx;
  bx = s - q * gx;
  by = xcd * 4 + q;
}

// ---------------- 128x128 GEMM core — BK=64, swizzled, double-buffered ----------------
__device__ __forceinline__ void gemm_core(const u16* __restrict__ A, const u16* __restrict__ Bt,
                                          int K, int lda, int ldb, size_t bm, size_t bn,
                                          u16 (&As)[2][8192], u16 (&Bs)[2][8192],
                                          f32x4 (&acc)[4][4]) {
  const int tid = threadIdx.x;
  const int lane = tid & 63;
  const int wave = tid >> 6;
  const int wr = wave >> 1, wc = wave & 1;
  const int arow = wr * 64 + (lane & 15);
  const int bcol = wc * 64 + (lane & 15);
  const int nt = K >> 6;

  auto STAGE = [&](int t, int bi) {
    const int k0 = t << 6;
#pragma unroll
    for (int c4 = 0; c4 < 4; ++c4) {
      const int o = (c4 * 256 + tid) * 16;
      const int r = o >> 7;
      const int sc = (((o >> 4) & 7) ^ (r & 7)) << 3;
      gload_lds16(A + (bm + r) * lda + k0 + sc, &As[bi][o >> 1]);
      gload_lds16(Bt + (bn + r) * ldb + k0 + sc, &Bs[bi][o >> 1]);
    }
  };

  STAGE(0, 0);
  for (int t = 0; t < nt; ++t) {
    const int cur = t & 1;
    if (t + 1 < nt) {
      STAGE(t + 1, cur ^ 1);
      asm volatile("s_waitcnt vmcnt(8)" ::: "memory");
    } else {
      asm volatile("s_waitcnt vmcnt(0)" ::: "memory");
    }
    __builtin_amdgcn_s_barrier();
    asm volatile("" ::: "memory");
    bf16x8 af[4][2], bfr[4][2];
#pragma unroll
    for (int i = 0; i < 4; ++i)
#pragma unroll
      for (int ks = 0; ks < 2; ++ks) {
        const int ar = arow + i * 16;
        const int ac = ((ks * 4 + (lane >> 4)) ^ (ar & 7)) << 4;
        af[i][ks] = *(const bf16x8*)((const char*)&As[cur][0] + ar * 128 + ac);
        const int br = bcol + i * 16;
        const int bc = ((ks * 4 + (lane >> 4)) ^ (br & 7)) << 4;
        bfr[i][ks] = *(const bf16x8*)((const char*)&Bs[cur][0] + br * 128 + bc);
      }
#pragma unroll
    for (int ks = 0; ks < 2; ++ks)
#pragma unroll
      for (int i = 0; i < 4; ++i)
#pragma unroll
        for (int j = 0; j < 4; ++j)
          acc[i][j] = __builtin_amdgcn_mfma_f32_16x16x32_bf16(af[i][ks], bfr[j][ks],
                                                              acc[i][j], 0, 0, 0);
    asm volatile("s_waitcnt lgkmcnt(0)" ::: "memory");
    __builtin_amdgcn_sched_barrier(0);
    __builtin_amdgcn_s_barrier();
  }
}

// fat GEMM: bx<4 -> y panel (split-bf16, K=1536, f32 out); else xW panel (K=512, bf16)
__global__ __launch_bounds__(256, 2) void fat_gemm(const u16* __restrict__ Aatt,
                                                   const u16* __restrict__ Wt1,
                                                   const u16* __restrict__ Batt,
                                                   u16* __restrict__ xW, float* __restrict__ y) {
  __shared__ u16 As[2][8192];
  __shared__ u16 Bs[2][8192];
  f32x4 acc[4][4] = {};
  const int tid = threadIdx.x;
  const int lane = tid & 63;
  const int wave = tid >> 6;
  const int wr = wave >> 1, wc = wave & 1;
  int bx = blockIdx.x, by = blockIdx.y;
  xcd_align(20, bx, by);
  const size_t bm = (size_t)by * 128;
  const bool yp = bx < 4;
  const size_t bn = yp ? (size_t)bx * 128 : (size_t)(bx - 4) * 128;

  if (yp)
    gemm_core(Aatt, Batt, 1536, 1536, 1536, bm, bn, As, Bs, acc);
  else
    gemm_core(Aatt, Wt1, 512, 1536, 512, bm, bn, As, Bs, acc);

  const size_t crow = bm + wr * 64 + ((lane >> 4) * 4);
  const size_t ccol = bn + wc * 64 + (lane & 15);
#pragma unroll
  for (int i = 0; i < 4; ++i)
#pragma unroll
    for (int j = 0; j < 4; ++j)
#pragma unroll
      for (int b = 0; b < 4; ++b) {
        size_t r = crow + i * 16 + b, c = ccol + j * 16;
        if (yp)
          y[r * 512 + c] = acc[i][j][b];
        else
          xW[r * 2048 + c] = f2bf(acc[i][j][b]);
      }
}

// layer-2 GEMM: h1W = h1 @ Wt2^T, K=512, bf16 out, ldc=2048
__global__ __launch_bounds__(256, 2) void gemm_l2(const u16* __restrict__ h1,
                                                  const u16* __restrict__ Wt2,
                                                  u16* __restrict__ h1W) {
  __shared__ u16 As[2][8192];
  __shared__ u16 Bs[2][8192];
  f32x4 acc[4][4] = {};
  const int tid = threadIdx.x;
  const int lane = tid & 63;
  const int wave = tid >> 6;
  const int wr = wave >> 1, wc = wave & 1;
  int bx = blockIdx.x, by = blockIdx.y;
  xcd_align(16, bx, by);
  const size_t bm = (size_t)by * 128;
  const size_t bn = (size_t)bx * 128;
  gemm_core(h1, Wt2, 512, 512, 512, bm, bn, As, Bs, acc);
  const size_t crow = bm + wr * 64 + ((lane >> 4) * 4);
  const size_t ccol = bn + wc * 64 + (lane & 15);
#pragma unroll
  for (int i = 0; i < 4; ++i)
#pragma unroll
    for (int j = 0; j < 4; ++j)
#pragma unroll
      for (int b = 0; b < 4; ++b) {
        size_t r = crow + i * 16 + b, c = ccol + j * 16;
        h1W[r * 2048 + c] = f2bf(acc[i][j][b]);
      }
}

// XCD-contiguous row mapping for 4096 one-row blocks (reader XCD = n>>9)
__device__ __forceinline__ int xcd_row(int b) { return (b & 7) * 512 + (b >> 3); }

// ---------------- gather1: scores + softmax + banded aggregate + relu ----------------
__global__ void gather1(const float* __restrict__ xp, const float* __restrict__ y,
                        const u16* __restrict__ xW, const int* __restrict__ spkp,
                        float* __restrict__ attn, u16* __restrict__ h1) {
  const int n = xcd_row(blockIdx.x);
  const int tid = threadIdx.x;
  __shared__ float ys[512];
  __shared__ float sc[21];
  __shared__ float av[21], apv[21], asv[21];
  __shared__ int sps[21];
  const int mysp = spkp[16 + n];
  ys[tid] = y[(size_t)n * 512 + tid];
  ys[tid + 256] = y[(size_t)n * 512 + tid + 256];
  if (tid < 21) sps[tid] = spkp[16 + n - 10 + tid];
  __syncthreads();
  const int wave = tid >> 6, lane = tid & 63;
  for (int w = wave; w < 21; w += 4) {
    const float* xm = xp + (size_t)(n + 6 + w) * 512;  // guards zero -> OOB dot = 0
    float p = 0.f;
#pragma unroll
    for (int i = 0; i < 8; ++i) p += xm[lane + i * 64] * ys[lane + i * 64];
#pragma unroll
    for (int off = 32; off; off >>= 1) p += __shfl_xor(p, off, 64);
    if (lane == 0) sc[w] = p;
  }
  __syncthreads();
  if (tid < 64) {
    float v = (tid < 21) ? sc[tid] : -1e30f;
    float mx = v;
#pragma unroll
    for (int off = 32; off; off >>= 1) mx = fmaxf(mx, __shfl_xor(mx, off, 64));
    float e = (tid < 21) ? __expf(v - mx) : 0.f;
    float sum = e;
#pragma unroll
    for (int off = 32; off; off >>= 1) sum += __shfl_xor(sum, off, 64);
    if (tid < 21) {
      int m = n + tid - 10;
      float a = (0 <= m && m < NN) ? (e / sum) : 0.f;
      av[tid] = a;
      apv[tid] = (tid >= 10) ? a : 0.f;
      asv[tid] = (sps[tid] == mysp) ? a : 0.f;
      attn[(size_t)n * 24 + tid] = a;
    }
  }
  __syncthreads();
  const u32* xW32 = (const u32*)xW;
  u32 hv = xW32[(size_t)n * 1024 + 768 + tid];
  float a0 = blo(hv), a1 = bhi(hv);
#pragma unroll
  for (int w = 0; w < 10; ++w) {  // pred weight 0: 2 terms
    const u32* row = xW32 + (ptrdiff_t)(n - 10 + w) * 1024 + tid;
    u32 vs = row[256], va = row[512];
    float s2 = asv[w], a = av[w];
    a0 += s2 * blo(vs) + a * blo(va);
    a1 += s2 * bhi(vs) + a * bhi(va);
  }
#pragma unroll
  for (int w = 10; w < 21; ++w) {  // 3 terms
    const u32* row = xW32 + (ptrdiff_t)(n - 10 + w) * 1024 + tid;
    u32 vp = row[0], vs = row[256], va = row[512];
    float ap = apv[w], s2 = asv[w], a = av[w];
    a0 += ap * blo(vp) + s2 * blo(vs) + a * blo(va);
    a1 += ap * bhi(vp) + s2 * bhi(vs) + a * bhi(va);
  }
  ((u32*)(h1 + (size_t)n * 512))[tid] = packbf(fmaxf(a0, 0.f), fmaxf(a1, 0.f));
}

// ---------------- gather2: banded aggregate + relu -> fp32 out ----------------
__global__ void gather2(const u16* __restrict__ h1W, const float* __restrict__ attn,
                        const int* __restrict__ spkp, float* __restrict__ out) {
  const int n = xcd_row(blockIdx.x);
  const int tid = threadIdx.x;
  __shared__ float av[21], apv[21], asv[21];
  if (tid < 21) {
    float a = attn[(size_t)n * 24 + tid];
    int sp = spkp[16 + n - 10 + tid];
    av[tid] = a;
    apv[tid] = (tid >= 10) ? a : 0.f;
    asv[tid] = (sp == spkp[16 + n]) ? a : 0.f;
  }
  __syncthreads();
  const u32* hW32 = (const u32*)h1W;
  u32 hv = hW32[(size_t)n * 1024 + 768 + tid];
  float a0 = blo(hv), a1 = bhi(hv);
#pragma unroll
  for (int w = 0; w < 10; ++w) {
    const u32* row = hW32 + (ptrdiff_t)(n - 10 + w) * 1024 + tid;
    u32 vs = row[256], va = row[512];
    float s2 = asv[w], a = av[w];
    a0 += s2 * blo(vs) + a * blo(va);
    a1 += s2 * bhi(vs) + a * bhi(va);
  }
#pragma unroll
  for (int w = 10; w < 21; ++w) {
    const u32* row = hW32 + (ptrdiff_t)(n - 10 + w) * 1024 + tid;
    u32 vp = row[0], vs = row[256], va = row[512];
    float ap = apv[w], s2 = asv[w], a = av[w];
    a0 += ap * blo(vp) + s2 * blo(vs) + a * blo(va);
    a1 += ap * bhi(vp) + s2 * bhi(vs) + a * bhi(va);
  }
  float* o = out + (size_t)n * 512 + tid * 2;
  o[0] = fmaxf(a0, 0.f);
  o[1] = fmaxf(a1, 0.f);
}

// ---------------- launch ----------------
extern "C" void kernel_launch(void* const* d_in, const int* in_sizes, int n_in,
                              void* d_out, int out_size, void* d_ws, size_t ws_size,
                              hipStream_t stream) {
  const float* x = (const float*)d_in[0];
  const int* spk = (const int*)d_in[1];
  const float* w_gc1 = (const float*)d_in[2];
  const float* w_gc2 = (const float*)d_in[3];
  const float* w_att = (const float*)d_in[4];
  const float* w_aggr1 = (const float*)d_in[5];
  const float* w_aggr2 = (const float*)d_in[6];

  char* p = (char*)d_ws;
  u16* Aatt = (u16*)p;  p += (size_t)NN * 1536 * 2;     // 12.6 MB
  u16* Batt = (u16*)p;  p += (size_t)512 * 1536 * 2;    // 1.6 MB
  u16* Wt1 = (u16*)p;   p += (size_t)2048 * 512 * 2;    // 2.1 MB
  u16* Wt2 = (u16*)p;   p += (size_t)2048 * 512 * 2;    // 2.1 MB
  float* xp = (float*)p; p += (size_t)4128 * 512 * 4;   // 8.5 MB
  float* y = (float*)p; p += (size_t)NN * 512 * 4;      // 8.4 MB
  float* attn = (float*)p; p += (size_t)NN * 24 * 4;    // 0.4 MB
  u16* xWg = (u16*)p;   p += (size_t)4128 * 2048 * 2;   // 16.9 MB
  u16* h1 = (u16*)p;    p += (size_t)NN * 512 * 2;      // 4.2 MB
  u16* h1Wg = (u16*)p;  p += (size_t)4128 * 2048 * 2;   // 16.9 MB
  int* spkp = (int*)p;  p += (size_t)4128 * 4;          // 16.5 KB (~73.6 MB total)

  u16* xW = xWg + (size_t)16 * 2048;
  u16* h1W = h1Wg + (size_t)16 * 2048;

  prep_all<<<17745, 256, 0, stream>>>(x, w_att, w_gc1, w_aggr1, w_gc2, w_aggr2, spk,
                                      Aatt, Batt, Wt1, Wt2, xp, (u32*)xWg, (u32*)h1Wg,
                                      spkp);

  fat_gemm<<<dim3(20, 32), 256, 0, stream>>>(Aatt, Wt1, Batt, xW, y);

  gather1<<<NN, 256, 0, stream>>>(xp, y, xW, spkp, attn, h1);

  gemm_l2<<<dim3(16, 32), 256, 0, stream>>>(h1, Wt2, h1W);

  gather2<<<NN, 256, 0, stream>>>(h1W, attn, spkp, (float*)d_out);
}